// Round 3
// baseline (437.008 us; speedup 1.0000x reference)
//
#include <hip/hip_runtime.h>
#include <hip/hip_bf16.h>

#define MPTS 50000
#define NPTS 100000
#define HH 32
#define KK 15
#define TM 16          // queries per block; 50000 = 16*3125
#define KC 1024        // phase-C K dim: 64 c * 16 k (k=15 zero pad)
#define WTP 1032       // wt_lds row stride (shorts): +16B pad -> phase-C A-reads 2-way (free)
#define WLP 40         // w_lds h-stride (shorts): 80 B rows -> b128 A-reads 2-way (free)

typedef __attribute__((ext_vector_type(8))) short short8;
typedef __attribute__((ext_vector_type(4))) float floatx4;

static __device__ __forceinline__ unsigned short f2bf(float f) {
    __hip_bfloat16 h = __float2bfloat16(f);
    return *reinterpret_cast<unsigned short*>(&h);
}

// ---- prep: W''[d][c*16+k] = bf16(weights[k][c][d]), k=15 row zeroed. 64x1024 bf16 = 128 KB
__global__ void prep_weights(const float* __restrict__ w, unsigned short* __restrict__ wbf) {
    const int i = blockIdx.x * 256 + threadIdx.x;       // 65536
    const int d = i >> 10, kc = i & (KC - 1);
    const int c = kc >> 4, k = kc & 15;
    const float v = (k < KK) ? w[k * 4096 + c * 64 + d] : 0.0f;
    wbf[i] = f2bf(v);
}

__global__ __launch_bounds__(256, 2) void kpconv_kernel(
    const float* __restrict__ q_points,   // (M,3)
    const float* __restrict__ s_points,   // (N,3)
    const float* __restrict__ s_feats,    // (N,64)
    const int*   __restrict__ nbr,        // (M,32)
    const unsigned short* __restrict__ wbf, // W'' (64,1024) bf16
    const float* __restrict__ kpts,       // (15,3)
    float* __restrict__ out)              // (M,64)
{
    const int t    = threadIdx.x;
    const int m0   = blockIdx.x * TM;
    const int lane = t & 63;
    const int wv   = t >> 6;          // wave id = c-tile (B) / d-tile (C)
    const int l15  = lane & 15;
    const int lq   = lane >> 4;       // quad 0..3

    __shared__ float q_lds[TM][3];
    __shared__ float kp_lds[KK][4];
    __shared__ int   idx_lds[TM][HH];
    __shared__ __align__(16) unsigned short w_lds[TM][16][WLP];   // A-op phase B, 20.5 KB
    __shared__ __align__(16) unsigned short wt_lds[TM][WTP];      // weighted [m][c*16+k], 33 KB
    __shared__ float invcnt[TM];

    // ---------------- Phase A: small loads ----------------
    if (t < TM * 3) q_lds[t / 3][t % 3] = q_points[m0 * 3 + t];
    if (t < KK * 3) kp_lds[t / 3][t % 3] = kpts[t];
    idx_lds[t >> 5][t & 31]           = nbr[m0 * HH + t];
    idx_lds[(t + 256) >> 5][t & 31]   = nbr[m0 * HH + t + 256];
    __syncthreads();

    // -------- Phase A2: kernel-point weights w_lds[m][k][h] (bf16), k=15 zero pad
#pragma unroll
    for (int s = 0; s < 2; s++) {
        const int it = s * 256 + t;
        const int m = it >> 5, h = it & 31;
        const int idx = idx_lds[m][h];
        float px = 1.0e6f, py = 1.0e6f, pz = 1.0e6f;
        if (idx < NPTS) {
            px = s_points[idx * 3 + 0];
            py = s_points[idx * 3 + 1];
            pz = s_points[idx * 3 + 2];
        }
        const float rx = px - q_lds[m][0];
        const float ry = py - q_lds[m][1];
        const float rz = pz - q_lds[m][2];
#pragma unroll
        for (int k = 0; k < KK; k++) {
            const float dx = rx - kp_lds[k][0];
            const float dy = ry - kp_lds[k][1];
            const float dz = rz - kp_lds[k][2];
            const float d2 = dx * dx + dy * dy + dz * dz;
            w_lds[m][k][h] = f2bf(fmaxf(1.0f - sqrtf(d2) * 0.5f, 0.0f));
        }
        w_lds[m][15][h] = 0;   // bf16 +0.0
    }
    __syncthreads();   // w_lds + idx_lds ready — LAST barrier before the m-loop ends

    // ---------------- barrier-free m-loop: direct transposed gather + MFMA ----------------
    const int c = wv * 16 + l15;      // this lane's feature channel (B col / D col)
#pragma unroll 4
    for (int m = 0; m < TM; m++) {
        // 8 neighbor indices for this lane's h-octet (broadcast b128 reads)
        int idxs[8];
        {
            const int4 ia = *(const int4*)&idx_lds[m][lq * 8];
            const int4 ib = *(const int4*)&idx_lds[m][lq * 8 + 4];
            idxs[0] = ia.x; idxs[1] = ia.y; idxs[2] = ia.z; idxs[3] = ia.w;
            idxs[4] = ib.x; idxs[5] = ib.y; idxs[6] = ib.z; idxs[7] = ib.w;
        }
        // transposed gather: f[j] = feats[h=lq*8+j][c]  (lanes l15: 64 B coalesced segments)
        float f[8];
#pragma unroll
        for (int j = 0; j < 8; j++)
            f[j] = (idxs[j] < NPTS) ? s_feats[idxs[j] * 64 + c] : 0.0f;

        // neighbor count for this m (one wave, rotating): exact numpy pairwise order
        if (wv == (m & 3)) {
            const int h = lane >> 1, p = lane & 1;     // 32 h x 2 half-rows
            const int ci = idx_lds[m][h];
            float4 r = make_float4(0.f, 0.f, 0.f, 0.f);
            if (ci < NPTS) {
                const float* row = &s_feats[ci * 64 + p * 4];
                r = *(const float4*)row;                       // i = 0
#pragma unroll
                for (int i = 1; i < 8; i++) {
                    const float4 x = *(const float4*)(row + i * 8);
                    r.x += x.x; r.y += x.y; r.z += x.z; r.w += x.w;   // strict fold per j
                }
            }
            float sp = (r.x + r.y) + (r.z + r.w);      // exact pairwise half-tree
            sp += __shfl_xor(sp, 1);                   // s0+s1 (f32 add commutative: exact)
            const unsigned long long b = __ballot((p == 0) && (sp > 0.0f));
            if (lane == 0) {
                const int cnt = __popcll(b);
                invcnt[m] = 1.0f / (float)(cnt < 1 ? 1 : cnt);
            }
        }

        // pack B fragment, MFMA, write weighted tile
        short8 bfr;
#pragma unroll
        for (int j = 0; j < 8; j++) bfr[j] = (short)f2bf(f[j]);
        const short8 a = *(const short8*)&w_lds[m][l15][lq * 8];
        floatx4 d = {0.f, 0.f, 0.f, 0.f};
        d = __builtin_amdgcn_mfma_f32_16x16x32_bf16(a, bfr, d, 0, 0, 0);
        ushort4 pk;
        pk.x = f2bf(d[0]); pk.y = f2bf(d[1]); pk.z = f2bf(d[2]); pk.w = f2bf(d[3]);
        *(ushort4*)&wt_lds[m][c * 16 + lq * 4] = pk;   // [m][c*16 + k0], k0 = lq*4
    }
    __syncthreads();   // wt_lds + invcnt ready

    // ---------------- Phase C: out[m][d] = sum_kc wt[m][kc] * W''[kc][d] ----------------
    {
        floatx4 acc = {0.f, 0.f, 0.f, 0.f};
        const unsigned short* ap = &wt_lds[l15][lq * 8];
        const unsigned short* bp = wbf + (wv * 16 + l15) * KC + lq * 8;
#pragma unroll 8
        for (int s = 0; s < KC / 32; s++) {
            const short8 a = *(const short8*)(ap + s * 32);
            const short8 b = *(const short8*)(bp + s * 32);
            acc = __builtin_amdgcn_mfma_f32_16x16x32_bf16(a, b, acc, 0, 0, 0);
        }
        const int d = wv * 16 + l15;
#pragma unroll
        for (int r = 0; r < 4; r++) {
            const int m = lq * 4 + r;
            out[(m0 + m) * 64 + d] = acc[r] * invcnt[m];
        }
    }
}

extern "C" void kernel_launch(void* const* d_in, const int* in_sizes, int n_in,
                              void* d_out, int out_size, void* d_ws, size_t ws_size,
                              hipStream_t stream) {
    const float* q_points = (const float*)d_in[0];
    const float* s_points = (const float*)d_in[1];
    const float* s_feats  = (const float*)d_in[2];
    const int*   nbr      = (const int*)d_in[3];
    const float* weights  = (const float*)d_in[4];
    const float* kpts     = (const float*)d_in[5];
    float* out = (float*)d_out;
    unsigned short* wbf = (unsigned short*)d_ws;   // 64*1024*2 = 128 KB

    prep_weights<<<64 * KC / 256, 256, 0, stream>>>(weights, wbf);
    kpconv_kernel<<<MPTS / TM, 256, 0, stream>>>(q_points, s_points, s_feats, nbr,
                                                 wbf, kpts, out);
}

// Round 4
// 223.962 us; speedup vs baseline: 1.9513x; 1.9513x over previous
//
#include <hip/hip_runtime.h>
#include <hip/hip_bf16.h>

#define MPTS 50000
#define NPTS 100000
#define HH 32
#define KK 15
#define TM 16          // queries per block; 50000 = 16*3125
#define KC 1024        // phase-C K dim: 64 c * 16 k (k=15 zero pad)
#define WTP 1032       // wt_lds row stride (shorts): phase-C A b128 reads at HW floor
#define WLP 40         // w_lds h-stride (shorts): 80 B rows, A-frag b128 at HW floor
#define FSP 66         // f32 stage row stride (floats): 66%32=2 -> B-frag b32 reads 2-way (free)

typedef __attribute__((ext_vector_type(8))) short short8;
typedef __attribute__((ext_vector_type(4))) float floatx4;

static __device__ __forceinline__ unsigned short f2bf(float f) {
    __hip_bfloat16 h = __float2bfloat16(f);
    return *reinterpret_cast<unsigned short*>(&h);
}

// ---- prep 1: W''[d][c*16+k] = bf16(weights[k][c][d]), k=15 row zeroed (128 KB in ws)
__global__ void prep_weights(const float* __restrict__ w, unsigned short* __restrict__ wbf) {
    const int i = blockIdx.x * 256 + threadIdx.x;       // 65536
    const int d = i >> 10, kc = i & (KC - 1);
    const int c = kc >> 4, k = kc & 15;
    const float v = (k < KK) ? w[k * 4096 + c * 64 + d] : 0.0f;
    wbf[i] = f2bf(v);
}

// ---- prep 2: exact numpy-pairwise-order row sums of s_feats (100K floats, 400 KB in ws)
__global__ void prep_rowsum(const float* __restrict__ sf, float* __restrict__ rs) {
    const int t = blockIdx.x * 256 + threadIdx.x;
    const int row = t >> 1, p = t & 1;                  // 2 lanes per row
    if (row >= NPTS) return;
    const float* base = sf + row * 64 + p * 4;          // p=0: j=0..3, p=1: j=4..7
    float4 r = *(const float4*)base;                    // i = 0
#pragma unroll
    for (int i = 1; i < 8; i++) {
        const float4 x = *(const float4*)(base + i * 8);
        r.x += x.x; r.y += x.y; r.z += x.z; r.w += x.w; // strict per-j fold, i ascending
    }
    float sp = (r.x + r.y) + (r.z + r.w);               // pairwise half-tree
    sp += __shfl_xor(sp, 1);                            // + other half (commutative: exact)
    if (p == 0) rs[row] = sp;
}

__global__ __launch_bounds__(256, 2) void kpconv_kernel(
    const float* __restrict__ q_points,     // (M,3)
    const float* __restrict__ s_points,     // (N,3)
    const float* __restrict__ s_feats,      // (N,64)
    const int*   __restrict__ nbr,          // (M,32)
    const unsigned short* __restrict__ wbf, // W'' (64,1024) bf16
    const float* __restrict__ kpts,         // (15,3)
    const float* __restrict__ rowsum,       // (N,) exact row sums
    float* __restrict__ out)                // (M,64)
{
    const int t    = threadIdx.x;
    const int m0   = blockIdx.x * TM;
    const int lane = t & 63;
    const int wv   = t >> 6;          // wave id = c-tile (B) / d-tile (C)
    const int l15  = lane & 15;
    const int lq   = lane >> 4;       // quad 0..3

    __shared__ float q_lds[TM][3];
    __shared__ float kp_lds[KK][4];
    __shared__ int   idx_lds[TM][HH];
    __shared__ __align__(16) unsigned short w_lds[TM][16][WLP];  // 20.5 KB
    __shared__ __align__(16) float fstage[2][HH][FSP];           // 16.9 KB, double-buffered
    __shared__ __align__(16) unsigned short wt_lds[TM][WTP];     // 33 KB
    __shared__ float invcnt[TM];

    // ---------------- Phase A: small loads ----------------
    if (t < TM * 3) q_lds[t / 3][t % 3] = q_points[m0 * 3 + t];
    if (t < KK * 3) kp_lds[t / 3][t % 3] = kpts[t];
    idx_lds[t >> 5][t & 31]         = nbr[m0 * HH + t];
    idx_lds[(t + 256) >> 5][t & 31] = nbr[m0 * HH + t + 256];
    __syncthreads();

    // -------- issue feats gather for m=0 (2 float4/thread; 16 lanes cover one 256 B row)
    const int gh = t >> 4, gc4 = (t & 15) * 4;     // slot t -> row gh; slot t+256 -> row gh+16
    float4 g0, g1;
    {
        const int i0 = idx_lds[0][gh];
        const int i1 = idx_lds[0][gh + 16];
        g0 = (i0 < NPTS) ? *(const float4*)&s_feats[i0 * 64 + gc4]
                         : make_float4(0.f, 0.f, 0.f, 0.f);
        g1 = (i1 < NPTS) ? *(const float4*)&s_feats[i1 * 64 + gc4]
                         : make_float4(0.f, 0.f, 0.f, 0.f);
    }

    // -------- Phase A2 (overlaps gather latency): kernel-point weights, k=15 zero pad
#pragma unroll
    for (int s = 0; s < 2; s++) {
        const int it = s * 256 + t;
        const int m = it >> 5, h = it & 31;
        const int idx = idx_lds[m][h];
        float px = 1.0e6f, py = 1.0e6f, pz = 1.0e6f;
        if (idx < NPTS) {
            px = s_points[idx * 3 + 0];
            py = s_points[idx * 3 + 1];
            pz = s_points[idx * 3 + 2];
        }
        const float rx = px - q_lds[m][0];
        const float ry = py - q_lds[m][1];
        const float rz = pz - q_lds[m][2];
#pragma unroll
        for (int k = 0; k < KK; k++) {
            const float dx = rx - kp_lds[k][0];
            const float dy = ry - kp_lds[k][1];
            const float dz = rz - kp_lds[k][2];
            const float d2 = dx * dx + dy * dy + dz * dz;
            w_lds[m][k][h] = f2bf(fmaxf(1.0f - sqrtf(d2) * 0.5f, 0.0f));
        }
        w_lds[m][15][h] = 0;   // bf16 +0.0
    }

    // -------- Phase A3: neighbor counts from precomputed row sums (ballot per m)
#pragma unroll
    for (int s = 0; s < 2; s++) {
        const int it = s * 256 + t;
        const int m = it >> 5, h = it & 31;      // wave covers exactly 2 m's (32 lanes each)
        const int idx = idx_lds[m][h];
        const bool ok = (idx < NPTS) && (rowsum[idx] > 0.0f);
        const unsigned long long b = __ballot(ok);
        if (h == 0) {
            const unsigned half = (unsigned)(b >> ((m & 1) * 32));
            const int cnt = __popc(half);
            invcnt[m] = 1.0f / (float)(cnt < 1 ? 1 : cnt);
        }
    }

    // -------- write m=0 gather into stage buffer 0 (aligned float2 pairs)
    {
        float* w0 = &fstage[0][gh][gc4];
        float* w1 = &fstage[0][gh + 16][gc4];
        *(float2*)(w0)     = make_float2(g0.x, g0.y);
        *(float2*)(w0 + 2) = make_float2(g0.z, g0.w);
        *(float2*)(w1)     = make_float2(g1.x, g1.y);
        *(float2*)(w1 + 2) = make_float2(g1.z, g1.w);
    }

    // ---------------- m-loop: ONE barrier per iteration, double-buffered stage ----------------
    const int c = wv * 16 + l15;      // this lane's feature channel (B col / D col)
#pragma unroll
    for (int m = 0; m < TM; m++) {
        __syncthreads();              // fstage[m&1] (+ m==0: w_lds/invcnt) visible to all
        const int mb = m & 1;

        // issue gather for m+1 (consumed at end of this body -> latency hidden in-iteration)
        if (m < TM - 1) {
            const int i0 = idx_lds[m + 1][gh];
            const int i1 = idx_lds[m + 1][gh + 16];
            g0 = (i0 < NPTS) ? *(const float4*)&s_feats[i0 * 64 + gc4]
                             : make_float4(0.f, 0.f, 0.f, 0.f);
            g1 = (i1 < NPTS) ? *(const float4*)&s_feats[i1 * 64 + gc4]
                             : make_float4(0.f, 0.f, 0.f, 0.f);
        }

        // B-fragment straight from f32 stage: 8 scalar b32 reads, 2-way banks (free)
        const float* bp = &fstage[mb][lq * 8][c];
        short8 bfr;
#pragma unroll
        for (int j = 0; j < 8; j++) bfr[j] = (short)f2bf(bp[j * FSP]);

        // A-fragment + MFMA + weighted-tile write
        const short8 a = *(const short8*)&w_lds[m][l15][lq * 8];
        floatx4 d = {0.f, 0.f, 0.f, 0.f};
        d = __builtin_amdgcn_mfma_f32_16x16x32_bf16(a, bfr, d, 0, 0, 0);
        ushort4 pk;
        pk.x = f2bf(d[0]); pk.y = f2bf(d[1]); pk.z = f2bf(d[2]); pk.w = f2bf(d[3]);
        *(ushort4*)&wt_lds[m][c * 16 + lq * 4] = pk;   // [m][c*16+k0], k0=lq*4

        // stage m+1 into the other buffer (safe: next barrier orders vs readers)
        if (m < TM - 1) {
            float* w0 = &fstage[mb ^ 1][gh][gc4];
            float* w1 = &fstage[mb ^ 1][gh + 16][gc4];
            *(float2*)(w0)     = make_float2(g0.x, g0.y);
            *(float2*)(w0 + 2) = make_float2(g0.z, g0.w);
            *(float2*)(w1)     = make_float2(g1.x, g1.y);
            *(float2*)(w1 + 2) = make_float2(g1.z, g1.w);
        }
    }
    __syncthreads();   // wt_lds ready

    // ---------------- Phase C: out[m][d] = sum_kc wt[m][kc] * W''[kc][d] ----------------
    {
        floatx4 acc = {0.f, 0.f, 0.f, 0.f};
        const unsigned short* ap = &wt_lds[l15][lq * 8];
        const unsigned short* bp = wbf + (wv * 16 + l15) * KC + lq * 8;
#pragma unroll 8
        for (int s = 0; s < KC / 32; s++) {
            const short8 a = *(const short8*)(ap + s * 32);
            const short8 b = *(const short8*)(bp + s * 32);
            acc = __builtin_amdgcn_mfma_f32_16x16x32_bf16(a, b, acc, 0, 0, 0);
        }
        const int d = wv * 16 + l15;
#pragma unroll
        for (int r = 0; r < 4; r++) {
            const int m = lq * 4 + r;
            out[(m0 + m) * 64 + d] = acc[r] * invcnt[m];
        }
    }
}

extern "C" void kernel_launch(void* const* d_in, const int* in_sizes, int n_in,
                              void* d_out, int out_size, void* d_ws, size_t ws_size,
                              hipStream_t stream) {
    const float* q_points = (const float*)d_in[0];
    const float* s_points = (const float*)d_in[1];
    const float* s_feats  = (const float*)d_in[2];
    const int*   nbr      = (const int*)d_in[3];
    const float* weights  = (const float*)d_in[4];
    const float* kpts     = (const float*)d_in[5];
    float* out = (float*)d_out;

    unsigned short* wbf = (unsigned short*)d_ws;                 // 128 KB
    float* rowsum = (float*)((char*)d_ws + 64 * KC * 2);         // 400 KB

    prep_weights<<<64 * KC / 256, 256, 0, stream>>>(weights, wbf);
    prep_rowsum<<<(2 * NPTS + 255) / 256, 256, 0, stream>>>(s_feats, rowsum);
    kpconv_kernel<<<MPTS / TM, 256, 0, stream>>>(q_points, s_points, s_feats, nbr,
                                                 wbf, kpts, rowsum, out);
}